// Round 6
// baseline (650.023 us; speedup 1.0000x reference)
//
#include <hip/hip_runtime.h>

// Problem constants (B,T,D,H fixed by the reference)
#define BATCH 4
#define SEQ   2048
#define DIM   1024
#define NH    16
#define DK    64
// 0.125 (1/sqrt(DK)) * log2(e): folded into Q so attention uses exp2f
#define QSCALE 0.18033688011112042f

typedef __bf16 bf16x8 __attribute__((ext_vector_type(8)));
typedef float  f32x4  __attribute__((ext_vector_type(4)));
typedef short  s16x4  __attribute__((ext_vector_type(4)));
typedef short  s16x8  __attribute__((ext_vector_type(8)));

__device__ __forceinline__ short f2b(float f) {
    unsigned u = __float_as_uint(f);
    u += 0x7FFFu + ((u >> 16) & 1u);   // RNE
    return (short)(u >> 16);
}

// Load 8 bf16 as shorts, bit-cast in-register (no type-punned memory access).
__device__ __forceinline__ bf16x8 ldb(const short* p) {
    s16x8 v = *(const s16x8*)p;
    return __builtin_bit_cast(bf16x8, v);
}

// async global->LDS, 16B per lane. LDS dest must be linear in lane order.
__device__ __forceinline__ void ld16(const void* g, void* l) {
    __builtin_amdgcn_global_load_lds(
        (__attribute__((address_space(1))) void*)(unsigned long long)g,
        (__attribute__((address_space(3))) void*)l, 16, 0, 0);
}

// ---------------------------------------------------------------------------
// Kernel 1: fp32 -> bf16 conversion of x, W_qkv, W_o
// ---------------------------------------------------------------------------
__global__ __launch_bounds__(256)
void cvt_all(const float* __restrict__ x, const float* __restrict__ wq,
             const float* __restrict__ wo,
             short* __restrict__ xb, short* __restrict__ wqb, short* __restrict__ wob)
{
    const int NX4 = (BATCH*SEQ*DIM) / 4;
    const int NQ4 = (3*DIM*DIM) / 4;
    const int NO4 = (DIM*DIM) / 4;
    const int total = NX4 + NQ4 + NO4;
    for (int u = blockIdx.x * blockDim.x + threadIdx.x; u < total;
         u += gridDim.x * blockDim.x) {
        const float* src; short* dst; int off;
        if (u < NX4)            { src = x;  dst = xb;  off = u; }
        else if (u < NX4 + NQ4) { src = wq; dst = wqb; off = u - NX4; }
        else                    { src = wo; dst = wob; off = u - NX4 - NQ4; }
        f32x4 v = *(const f32x4*)&src[(size_t)off * 4];
        s16x4 o;
        o[0] = f2b(v[0]); o[1] = f2b(v[1]); o[2] = f2b(v[2]); o[3] = f2b(v[3]);
        *(s16x4*)&dst[(size_t)off * 4] = o;
    }
}

// ---------------------------------------------------------------------------
// GEMM (C = A * B^T), m97 pattern: 128x128 tile, BK=64, 4 waves.
// A,B bf16 (shorts), K contiguous.
// QKV=true: scatter to Q (scaled, (B,H,T,DK)), K ((B,H,T,DK)), Vt ((B,H,DK,T)).
// QKV=false: write C as FP32 to Cf (d_out is float per reference dtype).
// ---------------------------------------------------------------------------
template<bool QKV>
__global__ __launch_bounds__(256)
void gemm_bt(const short* __restrict__ A, const short* __restrict__ Bm,
             int M, int N, int K,
             short* __restrict__ C0, short* __restrict__ C1, short* __restrict__ C2,
             float* __restrict__ Cf)
{
    __shared__ short As[128 * 64];
    __shared__ short Bs[128 * 64];
    const int tid  = threadIdx.x;
    const int lane = tid & 63;
    const int lr   = lane & 15;
    const int lg   = lane >> 4;
    const int wid  = tid >> 6;
    const int wr   = wid >> 1, wc = wid & 1;
    const long row0 = (long)blockIdx.y * 128;
    const long col0 = (long)blockIdx.x * 128;

    f32x4 acc[4][4] = {};

    for (int k0 = 0; k0 < K; k0 += 64) {
        #pragma unroll
        for (int i = 0; i < 4; ++i) {               // A tile: 128x64 bf16
            int off = (i * 256 + tid) * 8;
            int r = off >> 6, c = off & 63;
            ld16(&A[(row0 + r) * (long)K + k0 + c], &As[off]);
        }
        #pragma unroll
        for (int i = 0; i < 4; ++i) {               // B tile: 128x64 bf16
            int off = (i * 256 + tid) * 8;
            int r = off >> 6, c = off & 63;
            ld16(&Bm[(col0 + r) * (long)K + k0 + c], &Bs[off]);
        }
        __syncthreads();
        #pragma unroll
        for (int ks = 0; ks < 2; ++ks) {
            bf16x8 af[4], bfr[4];
            #pragma unroll
            for (int m = 0; m < 4; ++m)
                af[m] = ldb(&As[(wr*64 + m*16 + lr)*64 + ks*32 + lg*8]);
            #pragma unroll
            for (int n = 0; n < 4; ++n)
                bfr[n] = ldb(&Bs[(wc*64 + n*16 + lr)*64 + ks*32 + lg*8]);
            #pragma unroll
            for (int m = 0; m < 4; ++m)
                #pragma unroll
                for (int n = 0; n < 4; ++n)
                    acc[m][n] = __builtin_amdgcn_mfma_f32_16x16x32_bf16(
                        af[m], bfr[n], acc[m][n], 0, 0, 0);
        }
        __syncthreads();
    }

    // C/D layout: col = lane&15, row = (lane>>4)*4 + reg
    if (QKV) {
        #pragma unroll
        for (int n = 0; n < 4; ++n) {
            const int gn    = (int)col0 + wc*64 + n*16 + lr;   // 0..3071
            const int which = gn >> 10;                        // 0=Q 1=K 2=V
            const int wi    = gn & 1023;
            const int h = wi >> 6, dk = wi & 63;
            #pragma unroll
            for (int m = 0; m < 4; ++m) {
                const int gm0 = (int)row0 + wr*64 + m*16 + lg*4;
                const int b = gm0 >> 11, t0 = gm0 & 2047;
                if (which == 2) {
                    // V transposed: Vt[(b,h,dk,t)], 4 consecutive t -> 8B store
                    s16x4 v4;
                    #pragma unroll
                    for (int r = 0; r < 4; ++r) v4[r] = f2b(acc[m][n][r]);
                    *(s16x4*)&C2[((long)((b*NH + h)*DK + dk)) * SEQ + t0] = v4;
                } else {
                    short* dst = (which == 0) ? C0 : C1;
                    const float sc = (which == 0) ? QSCALE : 1.0f;
                    #pragma unroll
                    for (int r = 0; r < 4; ++r)
                        dst[((long)((b*NH + h)*SEQ + t0 + r)) * DK + dk] =
                            f2b(acc[m][n][r] * sc);
                }
            }
        }
    } else {
        // FP32 output (d_out dtype = reference output dtype = float32)
        #pragma unroll
        for (int m = 0; m < 4; ++m)
            #pragma unroll
            for (int r = 0; r < 4; ++r) {
                const long gm = row0 + wr*64 + m*16 + lg*4 + r;
                #pragma unroll
                for (int n = 0; n < 4; ++n)
                    Cf[gm * N + col0 + wc*64 + n*16 + lr] = acc[m][n][r];
            }
    }
}

// ---------------------------------------------------------------------------
// Kernel 3: causal flash attention (MFMA).
// grid = (SEQ/64, BATCH*NH), block = 256 (4 waves, 16 q-rows per wave).
// Q pre-scaled by 0.125*log2e; softmax via exp2f.
// Q,K: (B,H,T,DK) bf16.  V: transposed (B,H,DK,T) bf16.  O: (B,T,D) bf16.
// ---------------------------------------------------------------------------
__global__ __launch_bounds__(256)
void attn(const short* __restrict__ Qb, const short* __restrict__ Kb,
          const short* __restrict__ Vt, short* __restrict__ Ob)
{
    __shared__ short Pl[4][16 * 40];    // per-wave P buffer, stride 40 (16B rows)
    const int tid  = threadIdx.x;
    const int lane = tid & 63;
    const int lr   = lane & 15, lg = lane >> 4;
    const int wid  = tid >> 6;
    const int bh   = blockIdx.y;
    const int b    = bh >> 4, h = bh & 15;
    const int qbase = blockIdx.x * 64 + wid * 16;

    const short* Qh = Qb + (long)bh * (SEQ * DK);
    const short* Kh = Kb + (long)bh * (SEQ * DK);
    const short* Vh = Vt + (long)bh * (DK * SEQ);
    short* Pw = &Pl[wid][0];

    // Q fragments (A-operand): lane holds Q[qbase+lr][ks*32 + lg*8 + j]
    const bf16x8 qf0 = ldb(&Qh[(qbase + lr) * DK + lg * 8]);
    const bf16x8 qf1 = ldb(&Qh[(qbase + lr) * DK + 32 + lg * 8]);

    f32x4 o[4] = {};
    float mrow[4] = {-1e30f, -1e30f, -1e30f, -1e30f};
    float lrow[4] = {0.f, 0.f, 0.f, 0.f};

    const int ntiles = (qbase + 47) >> 5;   // cover keys 0..qbase+15
    for (int kt = 0; kt < ntiles; ++kt) {
        const int kb0 = kt << 5;
        // S = Q K^T  (16q x 32k), two 16-col subtiles
        f32x4 s0 = {}, s1 = {};
        {
            bf16x8 ka = ldb(&Kh[(kb0 + lr) * DK + lg * 8]);
            bf16x8 kb = ldb(&Kh[(kb0 + lr) * DK + 32 + lg * 8]);
            s0 = __builtin_amdgcn_mfma_f32_16x16x32_bf16(qf0, ka, s0, 0, 0, 0);
            s0 = __builtin_amdgcn_mfma_f32_16x16x32_bf16(qf1, kb, s0, 0, 0, 0);
            bf16x8 kc = ldb(&Kh[(kb0 + 16 + lr) * DK + lg * 8]);
            bf16x8 kd = ldb(&Kh[(kb0 + 16 + lr) * DK + 32 + lg * 8]);
            s1 = __builtin_amdgcn_mfma_f32_16x16x32_bf16(qf0, kc, s1, 0, 0, 0);
            s1 = __builtin_amdgcn_mfma_f32_16x16x32_bf16(qf1, kd, s1, 0, 0, 0);
        }
        #pragma unroll
        for (int r = 0; r < 4; ++r) {
            const int qg = qbase + lg * 4 + r;
            float v0 = (kb0 + lr      <= qg) ? s0[r] : -1e30f;
            float v1 = (kb0 + 16 + lr <= qg) ? s1[r] : -1e30f;
            float mx = fmaxf(v0, v1);
            mx = fmaxf(mx, __shfl_xor(mx, 1));
            mx = fmaxf(mx, __shfl_xor(mx, 2));
            mx = fmaxf(mx, __shfl_xor(mx, 4));
            mx = fmaxf(mx, __shfl_xor(mx, 8));
            const float mnew = fmaxf(mrow[r], mx);
            const float corr = exp2f(mrow[r] - mnew);
            mrow[r] = mnew;
            const float p0 = exp2f(v0 - mnew);
            const float p1 = exp2f(v1 - mnew);
            float rs = p0 + p1;
            rs += __shfl_xor(rs, 1);
            rs += __shfl_xor(rs, 2);
            rs += __shfl_xor(rs, 4);
            rs += __shfl_xor(rs, 8);
            lrow[r] = lrow[r] * corr + rs;
            o[0][r] *= corr; o[1][r] *= corr; o[2][r] *= corr; o[3][r] *= corr;
            Pw[(lg*4 + r)*40 + lr]      = f2b(p0);
            Pw[(lg*4 + r)*40 + 16 + lr] = f2b(p1);
        }
        // ds_writes above must complete & not be reordered vs the read below
        __builtin_amdgcn_sched_barrier(0);
        __builtin_amdgcn_s_waitcnt(0xC07F);   // lgkmcnt(0)
        __builtin_amdgcn_sched_barrier(0);
        // P as A-operand: lane holds P[lr][lg*8 + j]
        const bf16x8 pf = ldb(&Pw[lr*40 + lg*8]);
        #pragma unroll
        for (int n2 = 0; n2 < 4; ++n2) {
            // B-operand from Vt: lane holds V[kb0+lg*8+j][n2*16+lr]
            bf16x8 vf = ldb(&Vh[(n2*16 + lr) * SEQ + kb0 + lg*8]);
            o[n2] = __builtin_amdgcn_mfma_f32_16x16x32_bf16(pf, vf, o[n2], 0, 0, 0);
        }
    }

    #pragma unroll
    for (int r = 0; r < 4; ++r) {
        const int t = qbase + lg * 4 + r;
        const float inv = 1.0f / lrow[r];
        #pragma unroll
        for (int n2 = 0; n2 < 4; ++n2)
            Ob[((long)(b * SEQ + t)) * DIM + h * DK + n2 * 16 + lr] =
                f2b(o[n2][r] * inv);
    }
}

// ---------------------------------------------------------------------------
extern "C" void kernel_launch(void* const* d_in, const int* in_sizes, int n_in,
                              void* d_out, int out_size, void* d_ws, size_t ws_size,
                              hipStream_t stream) {
    // Inputs are FP32 (reference dtypes). Select by size to be order-robust.
    const float *x = nullptr, *wqkv = nullptr, *wo = nullptr;
    for (int i = 0; i < n_in; ++i) {
        if      (in_sizes[i] == BATCH*SEQ*DIM) x    = (const float*)d_in[i];
        else if (in_sizes[i] == 3*DIM*DIM)     wqkv = (const float*)d_in[i];
        else if (in_sizes[i] == DIM*DIM)       wo   = (const float*)d_in[i];
    }
    float* out = (float*)d_out;   // FP32 output (reference output dtype)

    // Workspace (72 MiB; Ob aliases Xb which is dead after the QKV GEMM)
    char* ws = (char*)d_ws;
    short* Xb  = (short*)(ws);                        // [ 0,16) MiB x bf16
    short* Wqb = (short*)(ws + (16u<<20));            // [16,22) W_qkv bf16
    short* Wob = (short*)(ws + (22u<<20));            // [22,24) W_o bf16
    short* Qb  = (short*)(ws + (24u<<20));            // [24,40) Q (B,H,T,DK) scaled
    short* Kb  = (short*)(ws + (40u<<20));            // [40,56) K (B,H,T,DK)
    short* Vt  = (short*)(ws + (56u<<20));            // [56,72) V (B,H,DK,T)
    short* Ob  = Xb;                                  // attn out (B,T,D)

    cvt_all<<<2048, 256, 0, stream>>>(x, wqkv, wo, Xb, Wqb, Wob);

    // QKV projection: M=8192, N=3072, K=1024
    gemm_bt<true><<<dim3(3*DIM/128, BATCH*SEQ/128), 256, 0, stream>>>(
        Xb, Wqb, BATCH*SEQ, 3*DIM, DIM, Qb, Kb, Vt, nullptr);

    attn<<<dim3(SEQ/64, BATCH*NH), 256, 0, stream>>>(Qb, Kb, Vt, Ob);

    // Output projection: M=8192, N=1024, K=1024 -> FP32 d_out
    gemm_bt<false><<<dim3(DIM/128, BATCH*SEQ/128), 256, 0, stream>>>(
        Ob, Wob, BATCH*SEQ, DIM, DIM, nullptr, nullptr, nullptr, out);
}